// Round 11
// baseline (322.634 us; speedup 1.0000x reference)
//
#include <hip/hip_runtime.h>

typedef unsigned short u16;
typedef __attribute__((ext_vector_type(8))) short short8;
typedef __attribute__((ext_vector_type(4))) float floatx4;

#define N_TOK 2048
#define DIM   2048
#define NH    32
#define NKVH  4
#define HD    64
#define KVD   256

// packed-region offsets in the u16 workspace
#define OFF_X   0
#define OFF_WQ  4194304
#define OFF_WK  8388608
#define OFF_WV  8912896
#define OFF_WO  9437184
#define OFF_QP  13631488
#define OFF_KP  17825792
#define OFF_VP  18350080
#define OFF_YB  18874368

__device__ __forceinline__ float bf2f(u16 u) {
  union { unsigned i; float f; } c; c.i = ((unsigned)u) << 16; return c.f;
}
__device__ __forceinline__ u16 f2bf(float f) {
  union { float f; unsigned i; } c; c.f = f;
  unsigned x = c.i;
  return (u16)((x + 0x7fffu + ((x >> 16) & 1u)) >> 16);
}

// async global->LDS, 16B per lane (dest = wave-uniform base + lane*16)
__device__ __forceinline__ void gload16(const u16* g, u16* l) {
#if defined(__has_builtin) && __has_builtin(__builtin_amdgcn_global_load_lds)
  __builtin_amdgcn_global_load_lds(
      (const __attribute__((address_space(1))) void*)g,
      (__attribute__((address_space(3))) void*)l, 16, 0, 0);
#else
  *(short8*)l = *(const short8*)g;
#endif
}

// ===========================================================================
// PACKED LAYOUT (u16 indices; lane = qq*16 + rr, qq=lane>>4, rr=lane&15):
//   P[(rf*64 + kc)*512 + lane*8 + j] = T[rf*16 + rr][kc*32 + qq*8 + j]
// Each (row-frag, k-subtile) = one contiguous 1KB chunk in MFMA lane order.
// ===========================================================================

// ---------------------------------------------------------------------------
// cvt_pack: fp32 -> bf16 + frag-pack of x, Wq, Wk, Wv, Wo.
// ---------------------------------------------------------------------------
__global__ __launch_bounds__(256) void cvt_pack(const float* __restrict__ x,
                                                const float* __restrict__ wq,
                                                const float* __restrict__ wk,
                                                const float* __restrict__ wv,
                                                const float* __restrict__ wo,
                                                u16* __restrict__ ws) {
  __shared__ __align__(16) u16 Ls[2048];
  const int tid = threadIdx.x;
  const int rfg = blockIdx.x >> 4;
  const int kcg = blockIdx.x & 15;
  const float* src; u16* dst; int lrf;
  if      (rfg < 128) { src = x;  dst = ws + OFF_X;  lrf = rfg; }
  else if (rfg < 256) { src = wq; dst = ws + OFF_WQ; lrf = rfg - 128; }
  else if (rfg < 272) { src = wk; dst = ws + OFF_WK; lrf = rfg - 256; }
  else if (rfg < 288) { src = wv; dst = ws + OFF_WV; lrf = rfg - 272; }
  else                { src = wo; dst = ws + OFF_WO; lrf = rfg - 288; }

  const int rr = tid >> 4, cb = tid & 15;       // row 0..15, col-8-block 0..15
  const float* s = src + (size_t)(lrf * 16 + rr) * DIM + kcg * 128 + cb * 8;
  float4 v0 = ((const float4*)s)[0];
  float4 v1 = ((const float4*)s)[1];
  ushort4 o0, o1;
  o0.x = f2bf(v0.x); o0.y = f2bf(v0.y); o0.z = f2bf(v0.z); o0.w = f2bf(v0.w);
  o1.x = f2bf(v1.x); o1.y = f2bf(v1.y); o1.z = f2bf(v1.z); o1.w = f2bf(v1.w);
  const int ch = cb >> 2, qq = cb & 3;
  u16* lp = &Ls[ch * 512 + (qq * 16 + rr) * 8];
  ((ushort4*)lp)[0] = o0;
  ((ushort4*)lp)[1] = o1;
  __syncthreads();
  const int och = tid >> 6, lane = tid & 63;
  *(short8*)(dst + ((size_t)(lrf * 64 + kcg * 4 + och)) * 512 + lane * 8) =
      *(const short8*)&Ls[och * 512 + lane * 8];
}

// ===========================================================================
// ATTENTION FRAG-PACKED LAYOUTS (unchanged):
//  Qp: [(h*64 + sq)*4 + i*2 + c]*512 + lane*8 + j
//  Kp: [((kvh*32 + kt)*8) + t*2 + c]*512 + lane*8 + j
//  Vp: [((kvh*32 + kt)*8) + s*4 + t]*512 + lane*8 + j
// ===========================================================================

// ---------------------------------------------------------------------------
// Fused QKV projection GEMM, 64x128 tiles, BK=64, packed sources, RoPE fused.
// 2-deep counted-vmcnt pipeline (R10).  Grid 640.
// ---------------------------------------------------------------------------
__global__ __launch_bounds__(256) void gemm_qkv(const u16* __restrict__ xp,
                                                const u16* __restrict__ Wqp,
                                                const u16* __restrict__ Wkp,
                                                const u16* __restrict__ Wvp,
                                                const float* __restrict__ cs,
                                                const float* __restrict__ sn,
                                                u16* __restrict__ Qp,
                                                u16* __restrict__ Kp,
                                                u16* __restrict__ Vp) {
  __shared__ __align__(16) u16 As[2][8 * 512];
  __shared__ __align__(16) u16 Bs[2][16 * 512];
  const int tid  = threadIdx.x;
  const int lane = tid & 63;
  const int w    = tid >> 6;
  const int r    = lane & 15, q = lane >> 4;
  const int tm = blockIdx.x & 31;
  const int tn = blockIdx.x >> 5;   // 0..19
  const int wm = w & 1, wn = w >> 1;

  const u16* Wp; int rfB0;
  if (tn < 16)      { Wp = Wqp; rfB0 = tn * 8; }
  else if (tn < 18) { Wp = Wkp; rfB0 = (tn - 16) * 8; }
  else              { Wp = Wvp; rfB0 = (tn - 18) * 8; }
  const int rfA0 = tm * 4;

  const int cA0 = w, cA1 = w + 4;
  const u16* aS0 = xp + ((size_t)(rfA0 + (cA0 >> 1)) * 64 + (cA0 & 1)) * 512 + lane * 8;
  const u16* aS1 = xp + ((size_t)(rfA0 + (cA1 >> 1)) * 64 + (cA1 & 1)) * 512 + lane * 8;
  const u16* bS[4];
#pragma unroll
  for (int j = 0; j < 4; ++j) {
    int ch = w + 4 * j;
    bS[j] = Wp + ((size_t)(rfB0 + (ch >> 1)) * 64 + (ch & 1)) * 512 + lane * 8;
  }

  floatx4 acc[2][4];
#pragma unroll
  for (int a = 0; a < 2; ++a)
#pragma unroll
    for (int b = 0; b < 4; ++b) acc[a][b] = (floatx4){0.f, 0.f, 0.f, 0.f};

  auto stage = [&](int b, int kt) {          // 6 contiguous 1KB wave loads
    const size_t ko = (size_t)(kt * 2) * 512;
    gload16(aS0 + ko, &As[b][cA0 * 512 + lane * 8]);
    gload16(aS1 + ko, &As[b][cA1 * 512 + lane * 8]);
#pragma unroll
    for (int j = 0; j < 4; ++j)
      gload16(bS[j] + ko, &Bs[b][(w + 4 * j) * 512 + lane * 8]);
  };

  stage(0, 0);
  stage(1, 1);
  int cb = 0;
  for (int kt = 0; kt < 32; ++kt) {
    if (kt < 31) asm volatile("s_waitcnt vmcnt(6)" ::: "memory");
    else         asm volatile("s_waitcnt vmcnt(0)" ::: "memory");
    __builtin_amdgcn_s_barrier();
    __builtin_amdgcn_sched_barrier(0);

    short8 af[2][2], bf[4][2];
#pragma unroll
    for (int mi = 0; mi < 2; ++mi)
#pragma unroll
      for (int c = 0; c < 2; ++c)
        af[mi][c] = *(const short8*)&As[cb][((wm * 2 + mi) * 2 + c) * 512 + lane * 8];
#pragma unroll
    for (int nj = 0; nj < 4; ++nj)
#pragma unroll
      for (int c = 0; c < 2; ++c)
        bf[nj][c] = *(const short8*)&Bs[cb][((wn * 4 + nj) * 2 + c) * 512 + lane * 8];
#pragma unroll
    for (int c = 0; c < 2; ++c)
#pragma unroll
      for (int mi = 0; mi < 2; ++mi)
#pragma unroll
        for (int nj = 0; nj < 4; ++nj)
          acc[mi][nj] = __builtin_amdgcn_mfma_f32_16x16x32_bf16(af[mi][c], bf[nj][c], acc[mi][nj], 0, 0, 0);

    __builtin_amdgcn_sched_barrier(0);
    __builtin_amdgcn_s_barrier();            // all waves done reading buf cb
    if (kt + 2 < 32) stage(cb, kt + 2);
    cb ^= 1;
  }

  if (tn < 18) {
    const int head = (tn < 16) ? (tn * 2 + wn) : ((tn - 16) * 2 + wn);
#pragma unroll
    for (int mi = 0; mi < 2; ++mi)
#pragma unroll
      for (int g = 0; g < 4; ++g) {
        int row = tm * 64 + wm * 32 + mi * 16 + 4 * q + g;   // token
        const float* crow  = cs + (size_t)row * 64;
        const float* srow2 = sn + (size_t)row * 64;
#pragma unroll
        for (int nj = 0; nj < 2; ++nj) {
          int d = nj * 16 + r;               // head-dim 0..31 (pairs with d+32)
          float x0 = acc[mi][nj][g];
          float x1 = acc[mi][nj + 2][g];
          float o0 = x0 * crow[d]      - x1 * srow2[d];
          float o1 = x1 * crow[d + 32] + x0 * srow2[d + 32];
          int qq = d >> 3, j = d & 7;
          int lslot = (qq * 16 + (row & 15)) * 8 + j;
          if (tn < 16) {
            int sq = row >> 5, ii = (row >> 4) & 1;
            size_t base = ((size_t)(head * 64 + sq) * 4 + ii * 2) * 512 + lslot;
            Qp[base]       = f2bf(o0);
            Qp[base + 512] = f2bf(o1);
          } else {
            int kt2 = row >> 6, t = (row >> 4) & 3;
            size_t base = ((size_t)(head * 32 + kt2) * 8 + t * 2) * 512 + lslot;
            Kp[base]       = f2bf(o0);
            Kp[base + 512] = f2bf(o1);
          }
        }
      }
  } else {
#pragma unroll
    for (int mi = 0; mi < 2; ++mi)
#pragma unroll
      for (int nj = 0; nj < 4; ++nj) {
        int col  = (tn - 18) * 128 + wn * 64 + nj * 16 + r;   // dim 0..255
        int kvh  = col >> 6;
        int t    = (col & 63) >> 4;
        int rr   = col & 15;
        int row0 = tm * 64 + wm * 32 + mi * 16 + 4 * q;       // token
        int kt2  = row0 >> 6;
        int wk   = row0 & 63;
        int s    = wk >> 5;
        int qq   = (wk & 31) >> 3;
        int j0   = wk & 7;
        uint2 pk;
        pk.x = (unsigned)f2bf(acc[mi][nj][0]) | ((unsigned)f2bf(acc[mi][nj][1]) << 16);
        pk.y = (unsigned)f2bf(acc[mi][nj][2]) | ((unsigned)f2bf(acc[mi][nj][3]) << 16);
        size_t idx = ((size_t)(kvh * 32 + kt2) * 8 + s * 4 + t) * 512 + (qq * 16 + rr) * 8 + j0;
        *(uint2*)(Vp + idx) = pk;
      }
  }
}

// ---------------------------------------------------------------------------
// Output GEMM, 64x128 tiles, BK=64, packed A + packed B, fp32 out.  Grid 512.
// ---------------------------------------------------------------------------
__global__ __launch_bounds__(256) void gemm_out(const u16* __restrict__ Ap,
                                                const u16* __restrict__ Wp,
                                                float* __restrict__ C) {
  __shared__ __align__(16) u16 As[2][8 * 512];
  __shared__ __align__(16) u16 Bs[2][16 * 512];
  const int tid  = threadIdx.x;
  const int lane = tid & 63;
  const int w    = tid >> 6;
  const int r    = lane & 15, q = lane >> 4;
  const int tn = blockIdx.x & 15;
  const int tm = blockIdx.x >> 4;
  const int wm = w & 1, wn = w >> 1;

  const int rfA0 = tm * 4, rfB0 = tn * 8;
  const int cA0 = w, cA1 = w + 4;
  const u16* aS0 = Ap + ((size_t)(rfA0 + (cA0 >> 1)) * 64 + (cA0 & 1)) * 512 + lane * 8;
  const u16* aS1 = Ap + ((size_t)(rfA0 + (cA1 >> 1)) * 64 + (cA1 & 1)) * 512 + lane * 8;
  const u16* bS[4];
#pragma unroll
  for (int j = 0; j < 4; ++j) {
    int ch = w + 4 * j;
    bS[j] = Wp + ((size_t)(rfB0 + (ch >> 1)) * 64 + (ch & 1)) * 512 + lane * 8;
  }

  floatx4 acc[2][4];
#pragma unroll
  for (int a = 0; a < 2; ++a)
#pragma unroll
    for (int b = 0; b < 4; ++b) acc[a][b] = (floatx4){0.f, 0.f, 0.f, 0.f};

  auto stage = [&](int b, int kt) {
    const size_t ko = (size_t)(kt * 2) * 512;
    gload16(aS0 + ko, &As[b][cA0 * 512 + lane * 8]);
    gload16(aS1 + ko, &As[b][cA1 * 512 + lane * 8]);
#pragma unroll
    for (int j = 0; j < 4; ++j)
      gload16(bS[j] + ko, &Bs[b][(w + 4 * j) * 512 + lane * 8]);
  };

  stage(0, 0);
  stage(1, 1);
  int cb = 0;
  for (int kt = 0; kt < 32; ++kt) {
    if (kt < 31) asm volatile("s_waitcnt vmcnt(6)" ::: "memory");
    else         asm volatile("s_waitcnt vmcnt(0)" ::: "memory");
    __builtin_amdgcn_s_barrier();
    __builtin_amdgcn_sched_barrier(0);

    short8 af[2][2], bf[4][2];
#pragma unroll
    for (int mi = 0; mi < 2; ++mi)
#pragma unroll
      for (int c = 0; c < 2; ++c)
        af[mi][c] = *(const short8*)&As[cb][((wm * 2 + mi) * 2 + c) * 512 + lane * 8];
#pragma unroll
    for (int nj = 0; nj < 4; ++nj)
#pragma unroll
      for (int c = 0; c < 2; ++c)
        bf[nj][c] = *(const short8*)&Bs[cb][((wn * 4 + nj) * 2 + c) * 512 + lane * 8];
#pragma unroll
    for (int c = 0; c < 2; ++c)
#pragma unroll
      for (int mi = 0; mi < 2; ++mi)
#pragma unroll
        for (int nj = 0; nj < 4; ++nj)
          acc[mi][nj] = __builtin_amdgcn_mfma_f32_16x16x32_bf16(af[mi][c], bf[nj][c], acc[mi][nj], 0, 0, 0);

    __builtin_amdgcn_sched_barrier(0);
    __builtin_amdgcn_s_barrier();
    if (kt + 2 < 32) stage(cb, kt + 2);
    cb ^= 1;
  }

#pragma unroll
  for (int mi = 0; mi < 2; ++mi)
#pragma unroll
    for (int g = 0; g < 4; ++g) {
      int row = tm * 64 + wm * 32 + mi * 16 + 4 * q + g;
#pragma unroll
      for (int nj = 0; nj < 4; ++nj)
        C[(size_t)row * DIM + tn * 128 + wn * 64 + nj * 16 + r] = acc[mi][nj][g];
    }
}

// ---------------------------------------------------------------------------
// 4-wave balanced pair-scheduled MFMA flash attention.
// Block p handles q-blocks {63-p, p} = exactly 33 key-tiles; the 4 waves
// stripe the combined tile list mod 4 (9/8/8/8).  All 1024 blocks resident
// (4 blocks/CU x 4 waves = 4 waves/SIMD).  Plain-exp partials combine
// exactly; 3-round LDS combine reuses two buffers (LDS ~36KB).
// ---------------------------------------------------------------------------
__global__ __launch_bounds__(256, 4) void attn_mfma(const u16* __restrict__ Qp,
                                                    const u16* __restrict__ Kp,
                                                    const u16* __restrict__ Vp,
                                                    u16* __restrict__ Ybp) {
  __shared__ __align__(16) u16 Pl[4][32][72];
  __shared__ float Cb0[32][66], Cb1[32][66];
  __shared__ float Lb0[2][64], Lb1[2][64];
  const int tid  = threadIdx.x;
  const int lane = tid & 63;
  const int w    = tid >> 6;       // 0..3
  const int r    = lane & 15;
  const int q    = lane >> 4;
  const int p    = blockIdx.x;     // 0..31 pair index
  const int h    = blockIdx.y;
  const int kvh  = h >> 3;
  const int jA   = 63 - p;         // heavy q-block
  const int jB   = p;              // light q-block
  const int baseqA = jA * 32, baseqB = jB * 32;
  const int tA = (jA >> 1) + 1, tB = (jB >> 1) + 1;   // tile counts (sum 33)
  const int ktmaxA = tA - 1, ktmaxB = tB - 1;

  // Q frags: one 1KB wave read each
  short8 qfA[2][2], qfB[2][2];
#pragma unroll
  for (int i = 0; i < 2; ++i)
#pragma unroll
    for (int c = 0; c < 2; ++c) {
      qfA[i][c] = *(const short8*)(Qp + ((size_t)(h * 64 + jA) * 4 + i * 2 + c) * 512 + lane * 8);
      qfB[i][c] = *(const short8*)(Qp + ((size_t)(h * 64 + jB) * 4 + i * 2 + c) * 512 + lane * 8);
    }

  floatx4 OA[2][4], OB[2][4];
  float lsumA[2], lsumB[2];
#pragma unroll
  for (int i = 0; i < 2; ++i) {
    lsumA[i] = 0.f; lsumB[i] = 0.f;
#pragma unroll
    for (int t = 0; t < 4; ++t) {
      OA[i][t] = (floatx4){0.f, 0.f, 0.f, 0.f};
      OB[i][t] = (floatx4){0.f, 0.f, 0.f, 0.f};
    }
  }

  const u16* Kbase = Kp + (size_t)(kvh * 32) * 8 * 512;
  const u16* Vbase = Vp + (size_t)(kvh * 32) * 8 * 512;

  auto loadK = [&](int kt, short8 (&kf)[4][2]) {
    const u16* kb = Kbase + (size_t)kt * 8 * 512 + lane * 8;
#pragma unroll
    for (int t = 0; t < 4; ++t) {
      kf[t][0] = *(const short8*)(kb + (t * 2 + 0) * 512);
      kf[t][1] = *(const short8*)(kb + (t * 2 + 1) * 512);
    }
  };

  auto body = [&](int kt, int ktmax, int baseq,
                  short8 (&qf)[2][2], floatx4 (&O)[2][4], float (&lsum)[2],
                  short8 (&kc)[4][2], short8 (&kn)[4][2]) {
    // V for CURRENT tile: issued first, consumed at the bottom
    short8 vb[2][4];
    {
      const u16* vbp = Vbase + (size_t)kt * 8 * 512 + lane * 8;
#pragma unroll
      for (int s = 0; s < 2; ++s)
#pragma unroll
        for (int t = 0; t < 4; ++t)
          vb[s][t] = *(const short8*)(vbp + (s * 4 + t) * 512);
    }

    // K for this wave's next tile (kt+4), clamped, branchless
    loadK(kt + 4 <= ktmax ? kt + 4 : ktmax, kn);

    // ---- S^T = K Q^T ----
    floatx4 ST[2][4];
#pragma unroll
    for (int i = 0; i < 2; ++i)
#pragma unroll
      for (int t = 0; t < 4; ++t) ST[i][t] = (floatx4){0.f, 0.f, 0.f, 0.f};
#pragma unroll
    for (int t = 0; t < 4; ++t)
#pragma unroll
      for (int i = 0; i < 2; ++i) {
        ST[i][t] = __builtin_amdgcn_mfma_f32_16x16x32_bf16(kc[t][0], qf[i][0], ST[i][t], 0, 0, 0);
        ST[i][t] = __builtin_amdgcn_mfma_f32_16x16x32_bf16(kc[t][1], qf[i][1], ST[i][t], 0, 0, 0);
      }

    // ---- causal mask (only the last tile of this q-block can clip) ----
    if (kt == ktmax) {
#pragma unroll
      for (int i = 0; i < 2; ++i) {
        int qrow = baseq + 16 * i + r;
#pragma unroll
        for (int t = 0; t < 4; ++t) {
          int key = kt * 64 + 16 * t + 4 * q;
#pragma unroll
          for (int g = 0; g < 4; ++g)
            if (key + g > qrow) ST[i][t][g] = -1e30f;
        }
      }
    }

    // ---- p = exp(scale*s); partial row-sums; packed P -> LDS ----
#pragma unroll
    for (int i = 0; i < 2; ++i)
#pragma unroll
      for (int t = 0; t < 4; ++t) {
        float p0 = __expf(0.125f * ST[i][t][0]);
        float p1 = __expf(0.125f * ST[i][t][1]);
        float p2 = __expf(0.125f * ST[i][t][2]);
        float p3 = __expf(0.125f * ST[i][t][3]);
        lsum[i] += (p0 + p1) + (p2 + p3);
        uint2 pk;
        pk.x = (unsigned)f2bf(p0) | ((unsigned)f2bf(p1) << 16);
        pk.y = (unsigned)f2bf(p2) | ((unsigned)f2bf(p3) << 16);
        *(uint2*)&Pl[w][16 * i + r][16 * t + 4 * q] = pk;   // ds_write_b64
      }

    // ---- O += P V ----
#pragma unroll
    for (int s = 0; s < 2; ++s)
#pragma unroll
      for (int i = 0; i < 2; ++i) {
        short8 pa = *(const short8*)&Pl[w][16 * i + r][32 * s + 8 * q];
#pragma unroll
        for (int t = 0; t < 4; ++t)
          O[i][t] = __builtin_amdgcn_mfma_f32_16x16x32_bf16(pa, vb[s][t], O[i][t], 0, 0, 0);
      }
  };

  auto runloop = [&](int start, int ktmax, int baseq,
                     short8 (&qf)[2][2], floatx4 (&O)[2][4], float (&lsum)[2]) {
    if (start > ktmax) return;
    short8 kA[4][2], kB[4][2];
    loadK(start, kA);
    for (int kt = start; kt <= ktmax; kt += 8) {
      body(kt, ktmax, baseq, qf, O, lsum, kA, kB);
      if (kt + 4 <= ktmax) body(kt + 4, ktmax, baseq, qf, O, lsum, kB, kA);
    }
  };

  // Wave w takes items [w::4] of the combined list [A-tiles..., B-tiles...]
  runloop(w, ktmaxA, baseqA, qfA, OA, lsumA);
  const int sB = (w - tA) & 3;   // parity continuation into the B-tiles
  runloop(sB, ktmaxB, baseqB, qfB, OB, lsumB);

  // ---- 4-way combine: w0 owns A, w1 owns B; 3 rounds over 2 buffers ----
  auto pubA = [&] {
#pragma unroll
    for (int i = 0; i < 2; ++i) {
#pragma unroll
      for (int t = 0; t < 4; ++t)
#pragma unroll
        for (int g = 0; g < 4; ++g)
          Cb0[(i * 4 + t) * 4 + g][lane] = OA[i][t][g];
      Lb0[i][lane] = lsumA[i];
    }
  };
  auto pubB = [&] {
#pragma unroll
    for (int i = 0; i < 2; ++i) {
#pragma unroll
      for (int t = 0; t < 4; ++t)
#pragma unroll
        for (int g = 0; g < 4; ++g)
          Cb1[(i * 4 + t) * 4 + g][lane] = OB[i][t][g];
      Lb1[i][lane] = lsumB[i];
    }
  };
  auto addA = [&] {
#pragma unroll
    for (int i = 0; i < 2; ++i) {
#pragma unroll
      for (int t = 0; t < 4; ++t)
#pragma unroll
        for (int g = 0; g < 4; ++g)
          OA[i][t][g] += Cb0[(i * 4 + t) * 4 + g][lane];
      lsumA[i] += Lb0[i][lane];
    }
  };
  auto addB = [&] {
#pragma unroll
    for (int i = 0; i < 2; ++i) {
#pragma unroll
      for (int t = 0; t < 4; ++t)
#pragma unroll
        for (int g = 0; g < 4; ++g)
          OB[i][t][g] += Cb1[(i * 4 + t) * 4 + g][lane];
      lsumB[i] += Lb1[i][lane];
    }
  };

  if (w == 2) pubA;
  if (w == 2) pubA();
  if (w == 3) pubB();
  __syncthreads();
  if (w == 0) addA();
  if (w == 1) addB();
  __syncthreads();
  if (w == 3) pubA();
  if (w == 2) pubB();
  __syncthreads();
  if (w == 0) addA();
  if (w == 1) addB();
  __syncthreads();
  if (w == 1) pubA();
  if (w == 0) pubB();
  __syncthreads();

  // finalize: normalize and store to PACKED Yb layout
  auto finalize = [&](int baseq, floatx4 (&O)[2][4], float (&lsum)[2]) {
#pragma unroll
    for (int i = 0; i < 2; ++i) {
      lsum[i] += __shfl_xor(lsum[i], 16);
      lsum[i] += __shfl_xor(lsum[i], 32);   // lane(q,r) holds sum for row r
    }
#pragma unroll
    for (int i = 0; i < 2; ++i) {
      float inv[4];
#pragma unroll
      for (int g = 0; g < 4; ++g)
        inv[g] = 1.f / __shfl(lsum[i], 4 * q + g);
#pragma unroll
      for (int g = 0; g < 4; ++g) {
        int rowi = baseq + 16 * i + 4 * q + g;
        size_t rbase = ((size_t)(rowi >> 4) * 64 + h * 2) * 512 +
                       (((r >> 3)) * 16 + (rowi & 15)) * 8 + (r & 7);
        Ybp[rbase]       = f2bf(O[i][0][g] * inv[g]);   // t=0
        Ybp[rbase + 256] = f2bf(O[i][1][g] * inv[g]);   // t=1
        Ybp[rbase + 512] = f2bf(O[i][2][g] * inv[g]);   // t=2
        Ybp[rbase + 768] = f2bf(O[i][3][g] * inv[g]);   // t=3
      }
    }
  };

  if (w == 0) {
    addA();
    finalize(baseqA, OA, lsumA);
  } else if (w == 1) {
    addB();
    finalize(baseqB, OB, lsumB);
  }
}

// ---------------------------------------------------------------------------
extern "C" void kernel_launch(void* const* d_in, const int* in_sizes, int n_in,
                              void* d_out, int out_size, void* d_ws, size_t ws_size,
                              hipStream_t stream) {
  const float* x  = (const float*)d_in[0];
  const float* Wq = (const float*)d_in[1];
  const float* Wk = (const float*)d_in[2];
  const float* Wv = (const float*)d_in[3];
  const float* Wo = (const float*)d_in[4];
  const float* cs = (const float*)d_in[5];
  const float* sn = (const float*)d_in[6];

  u16* ws  = (u16*)d_ws;
  u16* xp  = ws + OFF_X;
  u16* Wqp = ws + OFF_WQ;
  u16* Wkp = ws + OFF_WK;
  u16* Wvp = ws + OFF_WV;
  u16* Wop = ws + OFF_WO;
  u16* Qp  = ws + OFF_QP;
  u16* Kp  = ws + OFF_KP;
  u16* Vp  = ws + OFF_VP;
  u16* Ybp = ws + OFF_YB;

  // fp32 -> bf16 + frag-pack (x + 4 weights)
  cvt_pack<<<dim3(6656), 256, 0, stream>>>(x, Wq, Wk, Wv, Wo, ws);

  // Fused QKV projection + RoPE, packed in, frag-packed out
  gemm_qkv<<<dim3(640), 256, 0, stream>>>(xp, Wqp, Wkp, Wvp, cs, sn, Qp, Kp, Vp);

  // 4-wave balanced pair-scheduled attention, writes packed Yb
  attn_mfma<<<dim3(32, 32), 256, 0, stream>>>(Qp, Kp, Vp, Ybp);

  // Output projection (packed A and B, fp32 straight to d_out)
  gemm_out<<<dim3(512), 256, 0, stream>>>(Ybp, Wop, (float*)d_out);
}

// Round 12
// 191.992 us; speedup vs baseline: 1.6805x; 1.6805x over previous
//
#include <hip/hip_runtime.h>

typedef unsigned short u16;
typedef __attribute__((ext_vector_type(8))) short short8;
typedef __attribute__((ext_vector_type(4))) float floatx4;

#define N_TOK 2048
#define DIM   2048
#define NH    32
#define NKVH  4
#define HD    64
#define KVD   256

// packed-region offsets in the u16 workspace
#define OFF_X   0
#define OFF_WQ  4194304
#define OFF_WK  8388608
#define OFF_WV  8912896
#define OFF_WO  9437184
#define OFF_QP  13631488
#define OFF_KP  17825792
#define OFF_VP  18350080
#define OFF_YB  18874368

__device__ __forceinline__ float bf2f(u16 u) {
  union { unsigned i; float f; } c; c.i = ((unsigned)u) << 16; return c.f;
}
__device__ __forceinline__ u16 f2bf(float f) {
  union { float f; unsigned i; } c; c.f = f;
  unsigned x = c.i;
  return (u16)((x + 0x7fffu + ((x >> 16) & 1u)) >> 16);
}

// async global->LDS, 16B per lane (dest = wave-uniform base + lane*16)
__device__ __forceinline__ void gload16(const u16* g, u16* l) {
#if defined(__has_builtin) && __has_builtin(__builtin_amdgcn_global_load_lds)
  __builtin_amdgcn_global_load_lds(
      (const __attribute__((address_space(1))) void*)g,
      (__attribute__((address_space(3))) void*)l, 16, 0, 0);
#else
  *(short8*)l = *(const short8*)g;
#endif
}

// ===========================================================================
// PACKED LAYOUT (u16 indices; lane = qq*16 + rr, qq=lane>>4, rr=lane&15):
//   P[(rf*64 + kc)*512 + lane*8 + j] = T[rf*16 + rr][kc*32 + qq*8 + j]
// Each (row-frag, k-subtile) = one contiguous 1KB chunk in MFMA lane order.
// ===========================================================================

// ---------------------------------------------------------------------------
// cvt_pack: fp32 -> bf16 + frag-pack of x, Wq, Wk, Wv, Wo.
// ---------------------------------------------------------------------------
__global__ __launch_bounds__(256) void cvt_pack(const float* __restrict__ x,
                                                const float* __restrict__ wq,
                                                const float* __restrict__ wk,
                                                const float* __restrict__ wv,
                                                const float* __restrict__ wo,
                                                u16* __restrict__ ws) {
  __shared__ __align__(16) u16 Ls[2048];
  const int tid = threadIdx.x;
  const int rfg = blockIdx.x >> 4;
  const int kcg = blockIdx.x & 15;
  const float* src; u16* dst; int lrf;
  if      (rfg < 128) { src = x;  dst = ws + OFF_X;  lrf = rfg; }
  else if (rfg < 256) { src = wq; dst = ws + OFF_WQ; lrf = rfg - 128; }
  else if (rfg < 272) { src = wk; dst = ws + OFF_WK; lrf = rfg - 256; }
  else if (rfg < 288) { src = wv; dst = ws + OFF_WV; lrf = rfg - 272; }
  else                { src = wo; dst = ws + OFF_WO; lrf = rfg - 288; }

  const int rr = tid >> 4, cb = tid & 15;       // row 0..15, col-8-block 0..15
  const float* s = src + (size_t)(lrf * 16 + rr) * DIM + kcg * 128 + cb * 8;
  float4 v0 = ((const float4*)s)[0];
  float4 v1 = ((const float4*)s)[1];
  ushort4 o0, o1;
  o0.x = f2bf(v0.x); o0.y = f2bf(v0.y); o0.z = f2bf(v0.z); o0.w = f2bf(v0.w);
  o1.x = f2bf(v1.x); o1.y = f2bf(v1.y); o1.z = f2bf(v1.z); o1.w = f2bf(v1.w);
  const int ch = cb >> 2, qq = cb & 3;
  u16* lp = &Ls[ch * 512 + (qq * 16 + rr) * 8];
  ((ushort4*)lp)[0] = o0;
  ((ushort4*)lp)[1] = o1;
  __syncthreads();
  const int och = tid >> 6, lane = tid & 63;
  *(short8*)(dst + ((size_t)(lrf * 64 + kcg * 4 + och)) * 512 + lane * 8) =
      *(const short8*)&Ls[och * 512 + lane * 8];
}

// ===========================================================================
// ATTENTION FRAG-PACKED LAYOUTS (unchanged):
//  Qp: [(h*64 + sq)*4 + i*2 + c]*512 + lane*8 + j
//  Kp: [((kvh*32 + kt)*8) + t*2 + c]*512 + lane*8 + j
//  Vp: [((kvh*32 + kt)*8) + s*4 + t]*512 + lane*8 + j
// ===========================================================================

// ---------------------------------------------------------------------------
// Fused QKV projection GEMM, 64x128 tiles, BK=64, packed sources, RoPE fused.
// 2-deep counted-vmcnt pipeline (R10).  Grid 640.
// ---------------------------------------------------------------------------
__global__ __launch_bounds__(256) void gemm_qkv(const u16* __restrict__ xp,
                                                const u16* __restrict__ Wqp,
                                                const u16* __restrict__ Wkp,
                                                const u16* __restrict__ Wvp,
                                                const float* __restrict__ cs,
                                                const float* __restrict__ sn,
                                                u16* __restrict__ Qp,
                                                u16* __restrict__ Kp,
                                                u16* __restrict__ Vp) {
  __shared__ __align__(16) u16 As[2][8 * 512];
  __shared__ __align__(16) u16 Bs[2][16 * 512];
  const int tid  = threadIdx.x;
  const int lane = tid & 63;
  const int w    = tid >> 6;
  const int r    = lane & 15, q = lane >> 4;
  const int tm = blockIdx.x & 31;
  const int tn = blockIdx.x >> 5;   // 0..19
  const int wm = w & 1, wn = w >> 1;

  const u16* Wp; int rfB0;
  if (tn < 16)      { Wp = Wqp; rfB0 = tn * 8; }
  else if (tn < 18) { Wp = Wkp; rfB0 = (tn - 16) * 8; }
  else              { Wp = Wvp; rfB0 = (tn - 18) * 8; }
  const int rfA0 = tm * 4;

  const int cA0 = w, cA1 = w + 4;
  const u16* aS0 = xp + ((size_t)(rfA0 + (cA0 >> 1)) * 64 + (cA0 & 1)) * 512 + lane * 8;
  const u16* aS1 = xp + ((size_t)(rfA0 + (cA1 >> 1)) * 64 + (cA1 & 1)) * 512 + lane * 8;
  const u16* bS[4];
#pragma unroll
  for (int j = 0; j < 4; ++j) {
    int ch = w + 4 * j;
    bS[j] = Wp + ((size_t)(rfB0 + (ch >> 1)) * 64 + (ch & 1)) * 512 + lane * 8;
  }

  floatx4 acc[2][4];
#pragma unroll
  for (int a = 0; a < 2; ++a)
#pragma unroll
    for (int b = 0; b < 4; ++b) acc[a][b] = (floatx4){0.f, 0.f, 0.f, 0.f};

  auto stage = [&](int b, int kt) {          // 6 contiguous 1KB wave loads
    const size_t ko = (size_t)(kt * 2) * 512;
    gload16(aS0 + ko, &As[b][cA0 * 512 + lane * 8]);
    gload16(aS1 + ko, &As[b][cA1 * 512 + lane * 8]);
#pragma unroll
    for (int j = 0; j < 4; ++j)
      gload16(bS[j] + ko, &Bs[b][(w + 4 * j) * 512 + lane * 8]);
  };

  stage(0, 0);
  stage(1, 1);
  int cb = 0;
  for (int kt = 0; kt < 32; ++kt) {
    if (kt < 31) asm volatile("s_waitcnt vmcnt(6)" ::: "memory");
    else         asm volatile("s_waitcnt vmcnt(0)" ::: "memory");
    __builtin_amdgcn_s_barrier();
    __builtin_amdgcn_sched_barrier(0);

    short8 af[2][2], bf[4][2];
#pragma unroll
    for (int mi = 0; mi < 2; ++mi)
#pragma unroll
      for (int c = 0; c < 2; ++c)
        af[mi][c] = *(const short8*)&As[cb][((wm * 2 + mi) * 2 + c) * 512 + lane * 8];
#pragma unroll
    for (int nj = 0; nj < 4; ++nj)
#pragma unroll
      for (int c = 0; c < 2; ++c)
        bf[nj][c] = *(const short8*)&Bs[cb][((wn * 4 + nj) * 2 + c) * 512 + lane * 8];
#pragma unroll
    for (int c = 0; c < 2; ++c)
#pragma unroll
      for (int mi = 0; mi < 2; ++mi)
#pragma unroll
        for (int nj = 0; nj < 4; ++nj)
          acc[mi][nj] = __builtin_amdgcn_mfma_f32_16x16x32_bf16(af[mi][c], bf[nj][c], acc[mi][nj], 0, 0, 0);

    __builtin_amdgcn_sched_barrier(0);
    __builtin_amdgcn_s_barrier();            // all waves done reading buf cb
    if (kt + 2 < 32) stage(cb, kt + 2);
    cb ^= 1;
  }

  if (tn < 18) {
    const int head = (tn < 16) ? (tn * 2 + wn) : ((tn - 16) * 2 + wn);
#pragma unroll
    for (int mi = 0; mi < 2; ++mi)
#pragma unroll
      for (int g = 0; g < 4; ++g) {
        int row = tm * 64 + wm * 32 + mi * 16 + 4 * q + g;   // token
        const float* crow  = cs + (size_t)row * 64;
        const float* srow2 = sn + (size_t)row * 64;
#pragma unroll
        for (int nj = 0; nj < 2; ++nj) {
          int d = nj * 16 + r;               // head-dim 0..31 (pairs with d+32)
          float x0 = acc[mi][nj][g];
          float x1 = acc[mi][nj + 2][g];
          float o0 = x0 * crow[d]      - x1 * srow2[d];
          float o1 = x1 * crow[d + 32] + x0 * srow2[d + 32];
          int qq = d >> 3, j = d & 7;
          int lslot = (qq * 16 + (row & 15)) * 8 + j;
          if (tn < 16) {
            int sq = row >> 5, ii = (row >> 4) & 1;
            size_t base = ((size_t)(head * 64 + sq) * 4 + ii * 2) * 512 + lslot;
            Qp[base]       = f2bf(o0);
            Qp[base + 512] = f2bf(o1);
          } else {
            int kt2 = row >> 6, t = (row >> 4) & 3;
            size_t base = ((size_t)(head * 32 + kt2) * 8 + t * 2) * 512 + lslot;
            Kp[base]       = f2bf(o0);
            Kp[base + 512] = f2bf(o1);
          }
        }
      }
  } else {
#pragma unroll
    for (int mi = 0; mi < 2; ++mi)
#pragma unroll
      for (int nj = 0; nj < 4; ++nj) {
        int col  = (tn - 18) * 128 + wn * 64 + nj * 16 + r;   // dim 0..255
        int kvh  = col >> 6;
        int t    = (col & 63) >> 4;
        int rr   = col & 15;
        int row0 = tm * 64 + wm * 32 + mi * 16 + 4 * q;       // token
        int kt2  = row0 >> 6;
        int wk   = row0 & 63;
        int s    = wk >> 5;
        int qq   = (wk & 31) >> 3;
        int j0   = wk & 7;
        uint2 pk;
        pk.x = (unsigned)f2bf(acc[mi][nj][0]) | ((unsigned)f2bf(acc[mi][nj][1]) << 16);
        pk.y = (unsigned)f2bf(acc[mi][nj][2]) | ((unsigned)f2bf(acc[mi][nj][3]) << 16);
        size_t idx = ((size_t)(kvh * 32 + kt2) * 8 + s * 4 + t) * 512 + (qq * 16 + rr) * 8 + j0;
        *(uint2*)(Vp + idx) = pk;
      }
  }
}

// ---------------------------------------------------------------------------
// Output GEMM, 64x128 tiles, BK=64, packed A + packed B, fp32 out.  Grid 512.
// ---------------------------------------------------------------------------
__global__ __launch_bounds__(256) void gemm_out(const u16* __restrict__ Ap,
                                                const u16* __restrict__ Wp,
                                                float* __restrict__ C) {
  __shared__ __align__(16) u16 As[2][8 * 512];
  __shared__ __align__(16) u16 Bs[2][16 * 512];
  const int tid  = threadIdx.x;
  const int lane = tid & 63;
  const int w    = tid >> 6;
  const int r    = lane & 15, q = lane >> 4;
  const int tn = blockIdx.x & 15;
  const int tm = blockIdx.x >> 4;
  const int wm = w & 1, wn = w >> 1;

  const int rfA0 = tm * 4, rfB0 = tn * 8;
  const int cA0 = w, cA1 = w + 4;
  const u16* aS0 = Ap + ((size_t)(rfA0 + (cA0 >> 1)) * 64 + (cA0 & 1)) * 512 + lane * 8;
  const u16* aS1 = Ap + ((size_t)(rfA0 + (cA1 >> 1)) * 64 + (cA1 & 1)) * 512 + lane * 8;
  const u16* bS[4];
#pragma unroll
  for (int j = 0; j < 4; ++j) {
    int ch = w + 4 * j;
    bS[j] = Wp + ((size_t)(rfB0 + (ch >> 1)) * 64 + (ch & 1)) * 512 + lane * 8;
  }

  floatx4 acc[2][4];
#pragma unroll
  for (int a = 0; a < 2; ++a)
#pragma unroll
    for (int b = 0; b < 4; ++b) acc[a][b] = (floatx4){0.f, 0.f, 0.f, 0.f};

  auto stage = [&](int b, int kt) {
    const size_t ko = (size_t)(kt * 2) * 512;
    gload16(aS0 + ko, &As[b][cA0 * 512 + lane * 8]);
    gload16(aS1 + ko, &As[b][cA1 * 512 + lane * 8]);
#pragma unroll
    for (int j = 0; j < 4; ++j)
      gload16(bS[j] + ko, &Bs[b][(w + 4 * j) * 512 + lane * 8]);
  };

  stage(0, 0);
  stage(1, 1);
  int cb = 0;
  for (int kt = 0; kt < 32; ++kt) {
    if (kt < 31) asm volatile("s_waitcnt vmcnt(6)" ::: "memory");
    else         asm volatile("s_waitcnt vmcnt(0)" ::: "memory");
    __builtin_amdgcn_s_barrier();
    __builtin_amdgcn_sched_barrier(0);

    short8 af[2][2], bf[4][2];
#pragma unroll
    for (int mi = 0; mi < 2; ++mi)
#pragma unroll
      for (int c = 0; c < 2; ++c)
        af[mi][c] = *(const short8*)&As[cb][((wm * 2 + mi) * 2 + c) * 512 + lane * 8];
#pragma unroll
    for (int nj = 0; nj < 4; ++nj)
#pragma unroll
      for (int c = 0; c < 2; ++c)
        bf[nj][c] = *(const short8*)&Bs[cb][((wn * 4 + nj) * 2 + c) * 512 + lane * 8];
#pragma unroll
    for (int c = 0; c < 2; ++c)
#pragma unroll
      for (int mi = 0; mi < 2; ++mi)
#pragma unroll
        for (int nj = 0; nj < 4; ++nj)
          acc[mi][nj] = __builtin_amdgcn_mfma_f32_16x16x32_bf16(af[mi][c], bf[nj][c], acc[mi][nj], 0, 0, 0);

    __builtin_amdgcn_sched_barrier(0);
    __builtin_amdgcn_s_barrier();
    if (kt + 2 < 32) stage(cb, kt + 2);
    cb ^= 1;
  }

#pragma unroll
  for (int mi = 0; mi < 2; ++mi)
#pragma unroll
    for (int g = 0; g < 4; ++g) {
      int row = tm * 64 + wm * 32 + mi * 16 + 4 * q + g;
#pragma unroll
      for (int nj = 0; nj < 4; ++nj)
        C[(size_t)row * DIM + tn * 128 + wn * 64 + nj * 16 + r] = acc[mi][nj][g];
    }
}

// ---------------------------------------------------------------------------
// Balanced pair-scheduled MFMA flash attention (R10-proven, 2 waves/block),
// packed Yb output.  T5: s_setprio(1) around MFMA clusters (independent
// non-barrier waves -> scheduler can favor the MFMA-issuing wave).
// ---------------------------------------------------------------------------
__global__ __launch_bounds__(128, 2) void attn_mfma(const u16* __restrict__ Qp,
                                                    const u16* __restrict__ Kp,
                                                    const u16* __restrict__ Vp,
                                                    u16* __restrict__ Ybp) {
  __shared__ __align__(16) u16 Pl[2][32][72];
  __shared__ float OcA[32][66];   // wave1's partial for q-block A
  __shared__ float OcB[32][66];   // wave0's partial for q-block B
  __shared__ float LcA[2][64], LcB[2][64];
  const int tid  = threadIdx.x;
  const int lane = tid & 63;
  const int w    = tid >> 6;       // 0 or 1
  const int r    = lane & 15;
  const int q    = lane >> 4;
  const int p    = blockIdx.x;     // 0..31 pair index
  const int h    = blockIdx.y;
  const int kvh  = h >> 3;
  const int jA   = 63 - p;         // heavy q-block
  const int jB   = p;              // light q-block
  const int baseqA = jA * 32, baseqB = jB * 32;
  const int tA = (jA >> 1) + 1, tB = (jB >> 1) + 1;   // tile counts
  const int ktmaxA = tA - 1, ktmaxB = tB - 1;

  // Q frags: one 1KB wave read each (sq == j for 32-row q-blocks)
  short8 qfA[2][2], qfB[2][2];
#pragma unroll
  for (int i = 0; i < 2; ++i)
#pragma unroll
    for (int c = 0; c < 2; ++c) {
      qfA[i][c] = *(const short8*)(Qp + ((size_t)(h * 64 + jA) * 4 + i * 2 + c) * 512 + lane * 8);
      qfB[i][c] = *(const short8*)(Qp + ((size_t)(h * 64 + jB) * 4 + i * 2 + c) * 512 + lane * 8);
    }

  floatx4 OA[2][4], OB[2][4];
  float lsumA[2], lsumB[2];
#pragma unroll
  for (int i = 0; i < 2; ++i) {
    lsumA[i] = 0.f; lsumB[i] = 0.f;
#pragma unroll
    for (int t = 0; t < 4; ++t) {
      OA[i][t] = (floatx4){0.f, 0.f, 0.f, 0.f};
      OB[i][t] = (floatx4){0.f, 0.f, 0.f, 0.f};
    }
  }

  const u16* Kbase = Kp + (size_t)(kvh * 32) * 8 * 512;
  const u16* Vbase = Vp + (size_t)(kvh * 32) * 8 * 512;

  auto loadK = [&](int kt, short8 (&kf)[4][2]) {
    const u16* kb = Kbase + (size_t)kt * 8 * 512 + lane * 8;
#pragma unroll
    for (int t = 0; t < 4; ++t) {
      kf[t][0] = *(const short8*)(kb + (t * 2 + 0) * 512);
      kf[t][1] = *(const short8*)(kb + (t * 2 + 1) * 512);
    }
  };

  auto body = [&](int kt, int ktmax, int baseq,
                  short8 (&qf)[2][2], floatx4 (&O)[2][4], float (&lsum)[2],
                  short8 (&kc)[4][2], short8 (&kn)[4][2]) {
    // V for CURRENT tile: issued first, consumed at the bottom
    short8 vb[2][4];
    {
      const u16* vbp = Vbase + (size_t)kt * 8 * 512 + lane * 8;
#pragma unroll
      for (int s = 0; s < 2; ++s)
#pragma unroll
        for (int t = 0; t < 4; ++t)
          vb[s][t] = *(const short8*)(vbp + (s * 4 + t) * 512);
    }

    // K for this wave's next tile (kt+2), clamped, branchless
    loadK(kt + 2 <= ktmax ? kt + 2 : ktmax, kn);

    // ---- S^T = K Q^T ----
    floatx4 ST[2][4];
#pragma unroll
    for (int i = 0; i < 2; ++i)
#pragma unroll
      for (int t = 0; t < 4; ++t) ST[i][t] = (floatx4){0.f, 0.f, 0.f, 0.f};
    __builtin_amdgcn_s_setprio(1);
#pragma unroll
    for (int t = 0; t < 4; ++t)
#pragma unroll
      for (int i = 0; i < 2; ++i) {
        ST[i][t] = __builtin_amdgcn_mfma_f32_16x16x32_bf16(kc[t][0], qf[i][0], ST[i][t], 0, 0, 0);
        ST[i][t] = __builtin_amdgcn_mfma_f32_16x16x32_bf16(kc[t][1], qf[i][1], ST[i][t], 0, 0, 0);
      }
    __builtin_amdgcn_s_setprio(0);

    // ---- causal mask (only the last tile of this q-block can clip) ----
    if (kt == ktmax) {
#pragma unroll
      for (int i = 0; i < 2; ++i) {
        int qrow = baseq + 16 * i + r;
#pragma unroll
        for (int t = 0; t < 4; ++t) {
          int key = kt * 64 + 16 * t + 4 * q;
#pragma unroll
          for (int g = 0; g < 4; ++g)
            if (key + g > qrow) ST[i][t][g] = -1e30f;
        }
      }
    }

    // ---- p = exp(scale*s); partial row-sums; packed P -> LDS ----
#pragma unroll
    for (int i = 0; i < 2; ++i)
#pragma unroll
      for (int t = 0; t < 4; ++t) {
        float p0 = __expf(0.125f * ST[i][t][0]);
        float p1 = __expf(0.125f * ST[i][t][1]);
        float p2 = __expf(0.125f * ST[i][t][2]);
        float p3 = __expf(0.125f * ST[i][t][3]);
        lsum[i] += (p0 + p1) + (p2 + p3);
        uint2 pk;
        pk.x = (unsigned)f2bf(p0) | ((unsigned)f2bf(p1) << 16);
        pk.y = (unsigned)f2bf(p2) | ((unsigned)f2bf(p3) << 16);
        *(uint2*)&Pl[w][16 * i + r][16 * t + 4 * q] = pk;   // ds_write_b64
      }

    // ---- O += P V ----
    __builtin_amdgcn_s_setprio(1);
#pragma unroll
    for (int s = 0; s < 2; ++s)
#pragma unroll
      for (int i = 0; i < 2; ++i) {
        short8 pa = *(const short8*)&Pl[w][16 * i + r][32 * s + 8 * q];
#pragma unroll
        for (int t = 0; t < 4; ++t)
          O[i][t] = __builtin_amdgcn_mfma_f32_16x16x32_bf16(pa, vb[s][t], O[i][t], 0, 0, 0);
      }
    __builtin_amdgcn_s_setprio(0);
  };

  auto runloop = [&](int start, int ktmax, int baseq,
                     short8 (&qf)[2][2], floatx4 (&O)[2][4], float (&lsum)[2]) {
    if (start > ktmax) return;
    short8 kA[4][2], kB[4][2];
    loadK(start, kA);
    for (int kt = start; kt <= ktmax; kt += 4) {
      body(kt, ktmax, baseq, qf, O, lsum, kA, kB);
      if (kt + 2 <= ktmax) body(kt + 2, ktmax, baseq, qf, O, lsum, kB, kA);
    }
  };

  // Wave w takes items [w::2] of the combined list [A-tiles..., B-tiles...]
  runloop(w, ktmaxA, baseqA, qfA, OA, lsumA);
  const int sB = (w + tA) & 1;   // parity continuation into the B-tiles
  runloop(sB, ktmaxB, baseqB, qfB, OB, lsumB);

  // ---- cross-wave combine ----
  if (w == 1) {
#pragma unroll
    for (int i = 0; i < 2; ++i) {
#pragma unroll
      for (int t = 0; t < 4; ++t)
#pragma unroll
        for (int g = 0; g < 4; ++g)
          OcA[(i * 4 + t) * 4 + g][lane] = OA[i][t][g];
      LcA[i][lane] = lsumA[i];
    }
  } else {
#pragma unroll
    for (int i = 0; i < 2; ++i) {
#pragma unroll
      for (int t = 0; t < 4; ++t)
#pragma unroll
        for (int g = 0; g < 4; ++g)
          OcB[(i * 4 + t) * 4 + g][lane] = OB[i][t][g];
      LcB[i][lane] = lsumB[i];
    }
  }
  __syncthreads();

  // finalize: normalize and store to PACKED Yb layout
  auto finalize = [&](int baseq, floatx4 (&O)[2][4], float (&lsum)[2]) {
#pragma unroll
    for (int i = 0; i < 2; ++i) {
      lsum[i] += __shfl_xor(lsum[i], 16);
      lsum[i] += __shfl_xor(lsum[i], 32);   // lane(q,r) holds sum for row r
    }
#pragma unroll
    for (int i = 0; i < 2; ++i) {
      float inv[4];
#pragma unroll
      for (int g = 0; g < 4; ++g)
        inv[g] = 1.f / __shfl(lsum[i], 4 * q + g);
#pragma unroll
      for (int g = 0; g < 4; ++g) {
        int rowi = baseq + 16 * i + 4 * q + g;
        size_t rbase = ((size_t)(rowi >> 4) * 64 + h * 2) * 512 +
                       (((r >> 3)) * 16 + (rowi & 15)) * 8 + (r & 7);
        Ybp[rbase]       = f2bf(O[i][0][g] * inv[g]);   // t=0
        Ybp[rbase + 256] = f2bf(O[i][1][g] * inv[g]);   // t=1
        Ybp[rbase + 512] = f2bf(O[i][2][g] * inv[g]);   // t=2
        Ybp[rbase + 768] = f2bf(O[i][3][g] * inv[g]);   // t=3
      }
    }
  };

  if (w == 0) {
#pragma unroll
    for (int i = 0; i < 2; ++i) {
#pragma unroll
      for (int t = 0; t < 4; ++t)
#pragma unroll
        for (int g = 0; g < 4; ++g)
          OA[i][t][g] += OcA[(i * 4 + t) * 4 + g][lane];
      lsumA[i] += LcA[i][lane];
    }
    finalize(baseqA, OA, lsumA);
  } else {
#pragma unroll
    for (int i = 0; i < 2; ++i) {
#pragma unroll
      for (int t = 0; t < 4; ++t)
#pragma unroll
        for (int g = 0; g < 4; ++g)
          OB[i][t][g] += OcB[(i * 4 + t) * 4 + g][lane];
      lsumB[i] += LcB[i][lane];
    }
    finalize(baseqB, OB, lsumB);
  }
}

// ---------------------------------------------------------------------------
extern "C" void kernel_launch(void* const* d_in, const int* in_sizes, int n_in,
                              void* d_out, int out_size, void* d_ws, size_t ws_size,
                              hipStream_t stream) {
  const float* x  = (const float*)d_in[0];
  const float* Wq = (const float*)d_in[1];
  const float* Wk = (const float*)d_in[2];
  const float* Wv = (const float*)d_in[3];
  const float* Wo = (const float*)d_in[4];
  const float* cs = (const float*)d_in[5];
  const float* sn = (const float*)d_in[6];

  u16* ws  = (u16*)d_ws;
  u16* xp  = ws + OFF_X;
  u16* Wqp = ws + OFF_WQ;
  u16* Wkp = ws + OFF_WK;
  u16* Wvp = ws + OFF_WV;
  u16* Wop = ws + OFF_WO;
  u16* Qp  = ws + OFF_QP;
  u16* Kp  = ws + OFF_KP;
  u16* Vp  = ws + OFF_VP;
  u16* Ybp = ws + OFF_YB;

  // fp32 -> bf16 + frag-pack (x + 4 weights)
  cvt_pack<<<dim3(6656), 256, 0, stream>>>(x, Wq, Wk, Wv, Wo, ws);

  // Fused QKV projection + RoPE, packed in, frag-packed out
  gemm_qkv<<<dim3(640), 256, 0, stream>>>(xp, Wqp, Wkp, Wvp, cs, sn, Qp, Kp, Vp);

  // Balanced pair-scheduled attention (2 waves/block, R10-proven), packed Yb
  attn_mfma<<<dim3(32, 32), 128, 0, stream>>>(Qp, Kp, Vp, Ybp);

  // Output projection (packed A and B, fp32 straight to d_out)
  gemm_out<<<dim3(512), 256, 0, stream>>>(Ybp, Wop, (float*)d_out);
}